// Round 1
// baseline (431.341 us; speedup 1.0000x reference)
//
#include <hip/hip_runtime.h>

#define N_PTS 20000
#define NCLS 20
#define KNN 16
#define CAP 256            // per-row candidate buffer (expected count ~48-90)
#define R0 0.08305f        // radius giving E[count]=48 in the cube interior

// ---------------------------------------------------------------------------
// Kernel A: exact kNN (top-16 smallest euclidean d2, tie-break lower index)
// 1 wave = 4 rows; filter candidates with d2 < tau into LDS, then wave-level
// 16x argmin-extract. tau is an analytic, boundary-corrected estimate with a
// uniform retry loop for the (rare) under/overflow cases.
// ---------------------------------------------------------------------------
__global__ __launch_bounds__(256) void knn_kernel(const float* __restrict__ coords,
                                                  int* __restrict__ knn_out) {
    __shared__ unsigned long long buf[4][4][CAP];   // [wave][row][cand] = 32 KB
    const int lane = threadIdx.x & 63;
    const int wave = threadIdx.x >> 6;
    const int rowBase = (blockIdx.x * 4 + wave) * 4;

    float rx[4], ry[4], rz[4], tau[4];
#pragma unroll
    for (int rr = 0; rr < 4; ++rr) {
        const int row = rowBase + rr;
        const float x = coords[3 * row + 0];
        const float y = coords[3 * row + 1];
        const float z = coords[3 * row + 2];
        rx[rr] = x; ry[rr] = y; rz[rr] = z;
        // boundary-corrected radius: 2 fixed-point iterations on the
        // product-of-1D-overlap volume fraction (underestimates true clipped
        // ball volume -> overestimates tau -> safe side).
        float r = R0;
#pragma unroll
        for (int it = 0; it < 2; ++it) {
            const float inv2r = 0.5f / r;
            float fx = (fminf(x + r, 1.f) - fmaxf(x - r, 0.f)) * inv2r;
            float fy = (fminf(y + r, 1.f) - fmaxf(y - r, 0.f)) * inv2r;
            float fz = (fminf(z + r, 1.f) - fmaxf(z - r, 0.f)) * inv2r;
            float f = fminf(fx * fy * fz, 1.f);
            r = R0 * __powf(f, -0.33333334f);
        }
        tau[rr] = r * r;
    }

    unsigned scanMask = 0xFu;      // rows still needing a scan (wave-uniform)
    int mfin[4] = {0, 0, 0, 0};

    for (int attempt = 0; attempt < 8 && scanMask; ++attempt) {
        float tcur[4];
        int cnt[4];
#pragma unroll
        for (int rr = 0; rr < 4; ++rr) {
            tcur[rr] = ((scanMask >> rr) & 1u) ? tau[rr] : -1.f;  // d2>=0 never < -1
            cnt[rr] = 0;
        }
        for (int j0 = 0; j0 < N_PTS; j0 += 64) {
            const int j = j0 + lane;
            const bool jv = j < N_PTS;
            const int jc = jv ? j : 0;
            const float cx = coords[3 * jc + 0];
            const float cy = coords[3 * jc + 1];
            const float cz = coords[3 * jc + 2];
#pragma unroll
            for (int rr = 0; rr < 4; ++rr) {
                const float dx = cx - rx[rr];
                const float dy = cy - ry[rr];
                const float dz = cz - rz[rr];
                const float d2 = dx * dx + dy * dy + dz * dz;
                const bool take = jv && (d2 < tcur[rr]);
                const unsigned long long m = __ballot(take);
                if (take) {
                    const int pos = cnt[rr] + (int)__popcll(m & ((1ull << lane) - 1ull));
                    if (pos < CAP)
                        buf[wave][rr][pos] =
                            (((unsigned long long)__float_as_uint(d2)) << 32) | (unsigned)j;
                }
                cnt[rr] += (int)__popcll(m);
            }
        }
#pragma unroll
        for (int rr = 0; rr < 4; ++rr) {
            if (!((scanMask >> rr) & 1u)) continue;
            if (cnt[rr] > CAP) {            // overflow: shrink and rescan
                tau[rr] *= 0.4f;
                mfin[rr] = CAP;             // fallback if attempts exhausted
            } else if (cnt[rr] < KNN) {     // undercount: grow and rescan
                tau[rr] *= 3.0f;
                mfin[rr] = cnt[rr];
            } else {                        // accepted
                scanMask &= ~(1u << rr);
                mfin[rr] = cnt[rr];
            }
        }
    }

    // selection: 16 rounds of wave argmin-extract over packed (d2bits, idx)
#pragma unroll 1
    for (int rr = 0; rr < 4; ++rr) {
        int m = mfin[rr];
        if (m > CAP) m = CAP;
        unsigned long long e[CAP / 64];
#pragma unroll
        for (int i = 0; i < CAP / 64; ++i) {
            const int p = i * 64 + lane;
            e[i] = (p < m) ? buf[wave][rr][p] : ~0ull;
        }
        unsigned long long myKey = ~0ull;
        for (int r = 0; r < KNN; ++r) {
            unsigned long long lm = e[0];
#pragma unroll
            for (int i = 1; i < CAP / 64; ++i) lm = (e[i] < lm) ? e[i] : lm;
            unsigned long long gm = lm;
#pragma unroll
            for (int s = 32; s > 0; s >>= 1) {
                const unsigned long long o = __shfl_xor(gm, s, 64);
                gm = (o < gm) ? o : gm;
            }
#pragma unroll
            for (int i = 0; i < CAP / 64; ++i)
                if (e[i] == gm) e[i] = ~0ull;   // keys unique: one owner
            if (lane == r) myKey = gm;
        }
        if (lane < KNN)
            knn_out[(rowBase + rr) * KNN + lane] = (int)(unsigned)(myKey & 0xFFFFFFFFull);
    }
}

// ---------------------------------------------------------------------------
// Kernel B: row softmax of logits -> q0
// ---------------------------------------------------------------------------
__global__ __launch_bounds__(256) void softmax_kernel(const float* __restrict__ x,
                                                      float* __restrict__ q) {
    const int p = blockIdx.x * blockDim.x + threadIdx.x;
    if (p >= N_PTS) return;
    const float4* x4 = (const float4*)(x + p * NCLS);
    float v[NCLS];
#pragma unroll
    for (int t = 0; t < 5; ++t) {
        const float4 a = x4[t];
        v[4 * t + 0] = a.x; v[4 * t + 1] = a.y;
        v[4 * t + 2] = a.z; v[4 * t + 3] = a.w;
    }
    float mx = v[0];
#pragma unroll
    for (int c = 1; c < NCLS; ++c) mx = fmaxf(mx, v[c]);
    float s = 0.f;
#pragma unroll
    for (int c = 0; c < NCLS; ++c) { v[c] = __expf(v[c] - mx); s += v[c]; }
    const float inv = 1.f / s;
    float4* q4 = (float4*)(q + p * NCLS);
#pragma unroll
    for (int t = 0; t < 5; ++t) {
        float4 a;
        a.x = v[4 * t + 0] * inv; a.y = v[4 * t + 1] * inv;
        a.z = v[4 * t + 2] * inv; a.w = v[4 * t + 3] * inv;
        q4[t] = a;
    }
}

// ---------------------------------------------------------------------------
// Kernel C: one CRF iteration: gather 16 neighbour q-rows, mean, +logits,
// x @ W^T, softmax. One thread per point, everything in registers.
// ---------------------------------------------------------------------------
__global__ __launch_bounds__(256) void crf_iter_kernel(const float* __restrict__ logits,
                                                       const float* __restrict__ W,
                                                       const int* __restrict__ knn,
                                                       const float* __restrict__ qin,
                                                       float* __restrict__ qout,
                                                       float* __restrict__ refined_out) {
    __shared__ float Ws[NCLS * NCLS];
    for (int i = threadIdx.x; i < NCLS * NCLS; i += blockDim.x) Ws[i] = W[i];
    __syncthreads();
    const int p = blockIdx.x * blockDim.x + threadIdx.x;
    if (p >= N_PTS) return;

    float acc[NCLS];
#pragma unroll
    for (int c = 0; c < NCLS; ++c) acc[c] = 0.f;

    const int4* kn = (const int4*)(knn + p * KNN);
#pragma unroll
    for (int g = 0; g < 4; ++g) {
        const int4 k4 = kn[g];
        const int ids[4] = {k4.x, k4.y, k4.z, k4.w};
#pragma unroll
        for (int t = 0; t < 4; ++t) {
            unsigned id = (unsigned)ids[t];
            if (id >= N_PTS) id = 0;     // safety clamp (unreachable in practice)
            const float4* r4 = (const float4*)(qin + id * NCLS);
#pragma unroll
            for (int u = 0; u < 5; ++u) {
                const float4 a = r4[u];
                acc[4 * u + 0] += a.x; acc[4 * u + 1] += a.y;
                acc[4 * u + 2] += a.z; acc[4 * u + 3] += a.w;
            }
        }
    }

    float msg[NCLS];
#pragma unroll
    for (int c = 0; c < NCLS; ++c) msg[c] = acc[c] * (1.f / 16.f);

    float lg[NCLS];
    const float4* l4 = (const float4*)(logits + p * NCLS);
#pragma unroll
    for (int t = 0; t < 5; ++t) {
        const float4 a = l4[t];
        lg[4 * t + 0] = a.x; lg[4 * t + 1] = a.y;
        lg[4 * t + 2] = a.z; lg[4 * t + 3] = a.w;
    }

    float ref[NCLS];
#pragma unroll
    for (int c = 0; c < NCLS; ++c) {
        float s = lg[c];
#pragma unroll
        for (int k = 0; k < NCLS; ++k) s += msg[k] * Ws[c * NCLS + k];  // x @ W^T
        ref[c] = s;
    }

    if (refined_out != nullptr) {
        float4* r4 = (float4*)(refined_out + p * NCLS);
#pragma unroll
        for (int t = 0; t < 5; ++t) {
            float4 a;
            a.x = ref[4 * t + 0]; a.y = ref[4 * t + 1];
            a.z = ref[4 * t + 2]; a.w = ref[4 * t + 3];
            r4[t] = a;
        }
    }

    float mx = ref[0];
#pragma unroll
    for (int c = 1; c < NCLS; ++c) mx = fmaxf(mx, ref[c]);
    float s = 0.f;
    float ex[NCLS];
#pragma unroll
    for (int c = 0; c < NCLS; ++c) { ex[c] = __expf(ref[c] - mx); s += ex[c]; }
    const float inv = 1.f / s;
    float4* q4 = (float4*)(qout + p * NCLS);
#pragma unroll
    for (int t = 0; t < 5; ++t) {
        float4 a;
        a.x = ex[4 * t + 0] * inv; a.y = ex[4 * t + 1] * inv;
        a.z = ex[4 * t + 2] * inv; a.w = ex[4 * t + 3] * inv;
        q4[t] = a;
    }
}

// ---------------------------------------------------------------------------
extern "C" void kernel_launch(void* const* d_in, const int* in_sizes, int n_in,
                              void* d_out, int out_size, void* d_ws, size_t ws_size,
                              hipStream_t stream) {
    const float* logits = (const float*)d_in[0];   // (20000, 20)
    const float* coords = (const float*)d_in[1];   // (20000, 3)
    const float* W      = (const float*)d_in[2];   // (20, 20)
    float* out = (float*)d_out;                    // refined (400000) | q (400000)

    // workspace layout: knn indices | q ping | q pong  (~4.5 MB)
    int* knn = (int*)d_ws;
    float* q0 = (float*)((char*)d_ws + ((N_PTS * KNN * sizeof(int) + 255) & ~(size_t)255));
    float* q1 = q0 + N_PTS * NCLS;

    const int threads = 256;
    knn_kernel<<<N_PTS / 16, threads, 0, stream>>>(coords, knn);

    const int pblocks = (N_PTS + threads - 1) / threads;
    softmax_kernel<<<pblocks, threads, 0, stream>>>(logits, q0);

    crf_iter_kernel<<<pblocks, threads, 0, stream>>>(logits, W, knn, q0, q1, nullptr);
    crf_iter_kernel<<<pblocks, threads, 0, stream>>>(logits, W, knn, q1, q0, nullptr);
    crf_iter_kernel<<<pblocks, threads, 0, stream>>>(logits, W, knn, q0,
                                                     out + N_PTS * NCLS, out);
}

// Round 2
// 181.453 us; speedup vs baseline: 2.3771x; 2.3771x over previous
//
#include <hip/hip_runtime.h>

#define N_PTS 20000
#define NCLS 20
#define KNN 16
#define GRID 12
#define NCELLS (GRID * GRID * GRID)
#define HCELL (1.0f / (float)GRID)
#define CAP 128            // per-wave candidate buffer (E[count]~45 interior)

__device__ __forceinline__ int cell1d(float v) {
    int c = (int)(v * (float)GRID);
    return min(max(c, 0), GRID - 1);
}

// ---------------------------------------------------------------------------
// Grid build: histogram -> exclusive scan (1 block) -> scatter (counting sort)
// ---------------------------------------------------------------------------
__global__ __launch_bounds__(256) void count_kernel(const float* __restrict__ coords,
                                                    int* __restrict__ cellCount) {
    const int p = blockIdx.x * blockDim.x + threadIdx.x;
    if (p >= N_PTS) return;
    const int cx = cell1d(coords[3 * p + 0]);
    const int cy = cell1d(coords[3 * p + 1]);
    const int cz = cell1d(coords[3 * p + 2]);
    atomicAdd(&cellCount[(cz * GRID + cy) * GRID + cx], 1);
}

__global__ __launch_bounds__(256) void scan_kernel(const int* __restrict__ cellCount,
                                                   int* __restrict__ cellStart,
                                                   int* __restrict__ cellCursor) {
    __shared__ int part[256];
    const int t = threadIdx.x;
    const int base = t * 7;                   // 256*7 = 1792 >= 1728
    int local[7];
    int s = 0;
#pragma unroll
    for (int i = 0; i < 7; ++i) {
        const int c = base + i;
        const int v = (c < NCELLS) ? cellCount[c] : 0;
        local[i] = s;
        s += v;
    }
    part[t] = s;
    __syncthreads();
    for (int off = 1; off < 256; off <<= 1) {
        const int v = part[t] + ((t >= off) ? part[t - off] : 0);
        __syncthreads();
        part[t] = v;
        __syncthreads();
    }
    const int excl = (t > 0) ? part[t - 1] : 0;
#pragma unroll
    for (int i = 0; i < 7; ++i) {
        const int c = base + i;
        if (c < NCELLS) {
            cellStart[c] = excl + local[i];
            cellCursor[c] = excl + local[i];
        }
    }
    if (t == 255) cellStart[NCELLS] = part[255];
}

__global__ __launch_bounds__(256) void scatter_kernel(const float* __restrict__ coords,
                                                      int* __restrict__ cellCursor,
                                                      float4* __restrict__ sortedPts) {
    const int p = blockIdx.x * blockDim.x + threadIdx.x;
    if (p >= N_PTS) return;
    const float x = coords[3 * p + 0];
    const float y = coords[3 * p + 1];
    const float z = coords[3 * p + 2];
    const int c = (cell1d(z) * GRID + cell1d(y)) * GRID + cell1d(x);
    const int pos = atomicAdd(&cellCursor[c], 1);
    sortedPts[pos] = make_float4(x, y, z, __uint_as_float((unsigned)p));
}

// ---------------------------------------------------------------------------
// Grid kNN: one wave per (sorted) query point. Scan the (2*hw+1)^3 cell block
// with filter d2 < tau (tau <= (hw*h)^2 => coverage exact), ballot-append
// candidates to LDS, then 16x wave argmin-extract over packed (d2,idx) keys.
// Retry ladder: cnt<16 -> grow block; cnt>CAP -> shrink tau. Exact on accept.
// ---------------------------------------------------------------------------
__global__ __launch_bounds__(256) void knn_grid_kernel(const float4* __restrict__ sortedPts,
                                                       const int* __restrict__ cellStart,
                                                       int* __restrict__ knn_out) {
    __shared__ unsigned long long buf[4][CAP];   // 4 KB / block
    const int lane = threadIdx.x & 63;
    const int wave = threadIdx.x >> 6;
    const int s = blockIdx.x * 4 + wave;         // sorted position (N divisible by 4)

    const float4 qp = sortedPts[s];
    const float qx = qp.x, qy = qp.y, qz = qp.z;
    const unsigned oq = __float_as_uint(qp.w);   // original point index
    const int cx = cell1d(qx), cy = cell1d(qy), cz = cell1d(qz);
    const unsigned long long laneLt = (1ull << lane) - 1ull;

    float tau = (0.98f * HCELL) * (0.98f * HCELL);
    int hw = 1;
    int cnt = 0;

    for (int attempt = 0; attempt < 12; ++attempt) {
        cnt = 0;
        const int xlo = max(cx - hw, 0), xhi = min(cx + hw, GRID - 1);
        const int zlo = max(cz - hw, 0), zhi = min(cz + hw, GRID - 1);
        const int ylo = max(cy - hw, 0), yhi = min(cy + hw, GRID - 1);
        for (int zz = zlo; zz <= zhi; ++zz) {
            for (int yy = ylo; yy <= yhi; ++yy) {
                const int rowc = (zz * GRID + yy) * GRID;
                const int beg = cellStart[rowc + xlo];
                const int end = cellStart[rowc + xhi + 1];
                for (int j0 = beg; j0 < end; j0 += 64) {
                    const int j = j0 + lane;
                    const bool jv = j < end;
                    const float4 pt = sortedPts[jv ? j : beg];
                    const float dx = pt.x - qx;
                    const float dy = pt.y - qy;
                    const float dz = pt.z - qz;
                    const float d2 = dx * dx + dy * dy + dz * dz;
                    const bool take = jv && (d2 < tau);
                    const unsigned long long m = __ballot(take);
                    if (take) {
                        const int pos = cnt + (int)__popcll(m & laneLt);
                        if (pos < CAP)
                            buf[wave][pos] =
                                (((unsigned long long)__float_as_uint(d2)) << 32) |
                                (unsigned long long)__float_as_uint(pt.w);
                    }
                    cnt += (int)__popcll(m);
                }
            }
        }
        if (cnt >= KNN && cnt <= CAP) break;     // exact: d16 < sqrt(tau) <= hw*h
        if (cnt < KNN) {
            hw = min(hw + 1, GRID - 1);
            const float g = 0.98f * (float)hw * HCELL;
            tau = g * g;
        } else {
            tau *= 0.7f;
        }
    }

    // 16x argmin-extract over up to CAP keys (keys unique via idx bits)
    const int m = min(cnt, CAP);
    unsigned long long e0 = (lane < m) ? buf[wave][lane] : ~0ull;
    unsigned long long e1 = (lane + 64 < m) ? buf[wave][lane + 64] : ~0ull;
    unsigned long long myKey = ~0ull;
    for (int r = 0; r < KNN; ++r) {
        unsigned long long gm = (e0 < e1) ? e0 : e1;
#pragma unroll
        for (int sh = 32; sh > 0; sh >>= 1) {
            const unsigned long long o = __shfl_xor(gm, sh, 64);
            gm = (o < gm) ? o : gm;
        }
        if (e0 == gm) e0 = ~0ull;
        else if (e1 == gm) e1 = ~0ull;
        if (lane == r) myKey = gm;
    }
    if (lane < KNN)
        knn_out[oq * KNN + lane] = (int)(unsigned)(myKey & 0xFFFFFFFFull);
}

// ---------------------------------------------------------------------------
// Row softmax of logits -> q0
// ---------------------------------------------------------------------------
__global__ __launch_bounds__(256) void softmax_kernel(const float* __restrict__ x,
                                                      float* __restrict__ q) {
    const int p = blockIdx.x * blockDim.x + threadIdx.x;
    if (p >= N_PTS) return;
    const float4* x4 = (const float4*)(x + p * NCLS);
    float v[NCLS];
#pragma unroll
    for (int t = 0; t < 5; ++t) {
        const float4 a = x4[t];
        v[4 * t + 0] = a.x; v[4 * t + 1] = a.y;
        v[4 * t + 2] = a.z; v[4 * t + 3] = a.w;
    }
    float mx = v[0];
#pragma unroll
    for (int c = 1; c < NCLS; ++c) mx = fmaxf(mx, v[c]);
    float sum = 0.f;
#pragma unroll
    for (int c = 0; c < NCLS; ++c) { v[c] = __expf(v[c] - mx); sum += v[c]; }
    const float inv = 1.f / sum;
    float4* q4 = (float4*)(q + p * NCLS);
#pragma unroll
    for (int t = 0; t < 5; ++t) {
        float4 a;
        a.x = v[4 * t + 0] * inv; a.y = v[4 * t + 1] * inv;
        a.z = v[4 * t + 2] * inv; a.w = v[4 * t + 3] * inv;
        q4[t] = a;
    }
}

// ---------------------------------------------------------------------------
// One CRF iteration, 2 lanes per point (8 neighbour gathers each, shfl merge)
// ---------------------------------------------------------------------------
__global__ __launch_bounds__(256) void crf_iter_kernel(const float* __restrict__ logits,
                                                       const float* __restrict__ W,
                                                       const int* __restrict__ knn,
                                                       const float* __restrict__ qin,
                                                       float* __restrict__ qout,
                                                       float* __restrict__ refined_out) {
    __shared__ float Ws[NCLS * NCLS];
    for (int i = threadIdx.x; i < NCLS * NCLS; i += blockDim.x) Ws[i] = W[i];
    __syncthreads();
    const int t = blockIdx.x * blockDim.x + threadIdx.x;
    const int p = t >> 1;
    const int half = t & 1;
    if (p >= N_PTS) return;

    float acc[NCLS];
#pragma unroll
    for (int c = 0; c < NCLS; ++c) acc[c] = 0.f;

    const int4* kn = (const int4*)(knn + p * KNN + half * 8);
#pragma unroll
    for (int g = 0; g < 2; ++g) {
        const int4 k4 = kn[g];
        const int ids[4] = {k4.x, k4.y, k4.z, k4.w};
#pragma unroll
        for (int u = 0; u < 4; ++u) {
            unsigned id = (unsigned)ids[u];
            if (id >= N_PTS) id = 0;     // safety clamp (unreachable)
            const float4* r4 = (const float4*)(qin + id * NCLS);
#pragma unroll
            for (int v = 0; v < 5; ++v) {
                const float4 a = r4[v];
                acc[4 * v + 0] += a.x; acc[4 * v + 1] += a.y;
                acc[4 * v + 2] += a.z; acc[4 * v + 3] += a.w;
            }
        }
    }
    // merge the two halves (both lanes end with the full sum)
#pragma unroll
    for (int c = 0; c < NCLS; ++c) acc[c] += __shfl_xor(acc[c], 1, 64);

    float msg[NCLS];
#pragma unroll
    for (int c = 0; c < NCLS; ++c) msg[c] = acc[c] * (1.f / 16.f);

    float lg[NCLS];
    const float4* l4 = (const float4*)(logits + p * NCLS);
#pragma unroll
    for (int u = 0; u < 5; ++u) {
        const float4 a = l4[u];
        lg[4 * u + 0] = a.x; lg[4 * u + 1] = a.y;
        lg[4 * u + 2] = a.z; lg[4 * u + 3] = a.w;
    }

    float ref[NCLS];
#pragma unroll
    for (int c = 0; c < NCLS; ++c) {
        float s = lg[c];
#pragma unroll
        for (int k = 0; k < NCLS; ++k) s += msg[k] * Ws[c * NCLS + k];  // x @ W^T
        ref[c] = s;
    }

    if (half == 0 && refined_out != nullptr) {
        float4* r4 = (float4*)(refined_out + p * NCLS);
#pragma unroll
        for (int u = 0; u < 5; ++u) {
            float4 a;
            a.x = ref[4 * u + 0]; a.y = ref[4 * u + 1];
            a.z = ref[4 * u + 2]; a.w = ref[4 * u + 3];
            r4[u] = a;
        }
    }

    float mx = ref[0];
#pragma unroll
    for (int c = 1; c < NCLS; ++c) mx = fmaxf(mx, ref[c]);
    float sum = 0.f;
    float ex[NCLS];
#pragma unroll
    for (int c = 0; c < NCLS; ++c) { ex[c] = __expf(ref[c] - mx); sum += ex[c]; }
    const float inv = 1.f / sum;
    if (half == 1) {
        float4* q4 = (float4*)(qout + p * NCLS);
#pragma unroll
        for (int u = 0; u < 5; ++u) {
            float4 a;
            a.x = ex[4 * u + 0] * inv; a.y = ex[4 * u + 1] * inv;
            a.z = ex[4 * u + 2] * inv; a.w = ex[4 * u + 3] * inv;
            q4[u] = a;
        }
    }
}

// ---------------------------------------------------------------------------
extern "C" void kernel_launch(void* const* d_in, const int* in_sizes, int n_in,
                              void* d_out, int out_size, void* d_ws, size_t ws_size,
                              hipStream_t stream) {
    const float* logits = (const float*)d_in[0];   // (20000, 20)
    const float* coords = (const float*)d_in[1];   // (20000, 3)
    const float* W      = (const float*)d_in[2];   // (20, 20)
    float* out = (float*)d_out;                    // refined (400000) | q (400000)
    float* outHi = out + N_PTS * NCLS;             // q half; also ping-pong scratch

    // workspace layout (~3.2 MB)
    char* ws = (char*)d_ws;
    size_t off = 0;
    int* knn = (int*)(ws + off);            off += (size_t)N_PTS * KNN * 4;
    off = (off + 255) & ~(size_t)255;
    float* q0 = (float*)(ws + off);         off += (size_t)N_PTS * NCLS * 4;
    off = (off + 255) & ~(size_t)255;
    float4* sortedPts = (float4*)(ws + off); off += (size_t)N_PTS * 16;
    off = (off + 255) & ~(size_t)255;
    int* cellCount = (int*)(ws + off);      off += (size_t)NCELLS * 4;
    int* cellStart = (int*)(ws + off);      off += (size_t)(NCELLS + 1) * 4;
    int* cellCursor = (int*)(ws + off);

    const int threads = 256;
    const int pblocks = (N_PTS + threads - 1) / threads;

    hipMemsetAsync(cellCount, 0, NCELLS * sizeof(int), stream);
    count_kernel<<<pblocks, threads, 0, stream>>>(coords, cellCount);
    scan_kernel<<<1, threads, 0, stream>>>(cellCount, cellStart, cellCursor);
    scatter_kernel<<<pblocks, threads, 0, stream>>>(coords, cellCursor, sortedPts);
    knn_grid_kernel<<<N_PTS / 4, threads, 0, stream>>>(sortedPts, cellStart, knn);

    softmax_kernel<<<pblocks, threads, 0, stream>>>(logits, q0);

    const int cblocks = (2 * N_PTS + threads - 1) / threads;
    crf_iter_kernel<<<cblocks, threads, 0, stream>>>(logits, W, knn, q0, outHi, nullptr);
    crf_iter_kernel<<<cblocks, threads, 0, stream>>>(logits, W, knn, outHi, q0, nullptr);
    crf_iter_kernel<<<cblocks, threads, 0, stream>>>(logits, W, knn, q0, outHi, out);
}